// Round 6
// baseline (721.930 us; speedup 1.0000x reference)
//
#include <hip/hip_runtime.h>
#include <stdint.h>
#include <math.h>

#define NEG 0.2f
#define TINYF 1.1754943508222875e-38f

// ---------------- Threefry-2x32-20 (matches JAX) ----------------
__host__ __device__ inline void threefry2x32(uint32_t k0, uint32_t k1,
                                             uint32_t x0, uint32_t x1,
                                             uint32_t* o0, uint32_t* o1) {
  uint32_t ks0 = k0, ks1 = k1, ks2 = k0 ^ k1 ^ 0x1BD11BDAu;
  x0 += ks0; x1 += ks1;
#define RR(r) { x0 += x1; x1 = (x1 << (r)) | (x1 >> (32 - (r))); x1 ^= x0; }
  RR(13) RR(15) RR(26) RR(6)
  x0 += ks1; x1 += ks2 + 1u;
  RR(17) RR(29) RR(16) RR(24)
  x0 += ks2; x1 += ks0 + 2u;
  RR(13) RR(15) RR(26) RR(6)
  x0 += ks0; x1 += ks1 + 3u;
  RR(17) RR(29) RR(16) RR(24)
  x0 += ks1; x1 += ks2 + 4u;
  RR(13) RR(15) RR(26) RR(6)
  x0 += ks2; x1 += ks0 + 5u;
#undef RR
  *o0 = x0; *o1 = x1;
}

// jax_threefry_partitionable=True random_bits, bit_width=32:
//   bits[i] = o0 ^ o1 of TF(key, (0, i))   [verified exact: R3/R4/R5 pass]
__device__ inline float gumbel_part(uint32_t ka, uint32_t kb, uint32_t i) {
  uint32_t o0, o1;
  threefry2x32(ka, kb, 0u, i, &o0, &o1);
  uint32_t bits = o0 ^ o1;
  float f = __uint_as_float((bits >> 9) | 0x3f800000u) - 1.0f;
  float u = fmaxf(TINYF, f + TINYF);
  return -logf(-logf(u));
}

// ---------------- CSR build ----------------
__global__ void count_kernel(const int* __restrict__ ei, int E, int* __restrict__ counts) {
  int e = blockIdx.x * blockDim.x + threadIdx.x;
  if (e < E) atomicAdd(&counts[ei[E + e]], 1);
}

// wave-shuffle scan: 3 barriers per 1024-chunk
__global__ __launch_bounds__(1024) void scan_kernel(const int* __restrict__ counts,
    int* __restrict__ row_start, int* __restrict__ cursor, int N, int E) {
  __shared__ int wsum[16];
  __shared__ int base_s;
  int tid = threadIdx.x;
  int lane = tid & 63, wv = tid >> 6;
  if (tid == 0) base_s = 0;
  __syncthreads();
  for (int chunk = 0; chunk < N; chunk += 1024) {
    int i = chunk + tid;
    int v = (i < N) ? counts[i] : 0;
    int incl = v;
#pragma unroll
    for (int off = 1; off < 64; off <<= 1) {
      int t = __shfl_up(incl, off);
      if (lane >= off) incl += t;
    }
    if (lane == 63) wsum[wv] = incl;
    __syncthreads();
    if (wv == 0) {
      int x = (lane < 16) ? wsum[lane] : 0;
#pragma unroll
      for (int off = 1; off < 16; off <<= 1) {
        int t = __shfl_up(x, off);
        if (lane >= off) x += t;
      }
      if (lane < 16) wsum[lane] = x;  // inclusive wave sums
    }
    __syncthreads();
    int waveoff = (wv == 0) ? 0 : wsum[wv - 1];
    int base = base_s;
    int excl = base + waveoff + incl - v;
    if (i < N) { row_start[i] = excl; cursor[i] = excl; }
    __syncthreads();
    if (tid == 1023) base_s = base + wsum[15];
    __syncthreads();
  }
  if (tid == 0) row_start[N] = base_s;
}

__global__ void scatter_kernel(const int* __restrict__ ei, int E,
                               int* __restrict__ cursor, int* __restrict__ eid,
                               int* __restrict__ src_csr) {
  int e = blockIdx.x * blockDim.x + threadIdx.x;
  if (e < E) {
    int d = ei[E + e];
    int p = atomicAdd(&cursor[d], 1);
    eid[p] = e;
    src_csr[p] = ei[e];
  }
}

// ---------------- h = X @ W (128x128) + b ----------------
__global__ __launch_bounds__(256) void gemm128_kernel(const float* __restrict__ X,
    const float* __restrict__ W, const float* __restrict__ bias,
    float* __restrict__ out, int M) {
  __shared__ float xs[128][33];
  int row0 = blockIdx.x * 32;
  int tid = threadIdx.x;
  for (int idx = tid; idx < 32 * 128; idx += 256) {
    int r = idx >> 7;
    int k = idx & 127;
    int row = row0 + r;
    xs[k][r] = (row < M) ? X[(size_t)row * 128 + k] : 0.0f;
  }
  __syncthreads();
  int tc = tid & 31, tr = tid >> 5;
  int c0 = tc * 4, r0 = tr * 4;
  float acc[4][4] = {};
#pragma unroll 4
  for (int k = 0; k < 128; k++) {
    float4 w = *(const float4*)&W[k * 128 + c0];
    float x0 = xs[k][r0], x1 = xs[k][r0 + 1], x2 = xs[k][r0 + 2], x3 = xs[k][r0 + 3];
    acc[0][0] += x0 * w.x; acc[0][1] += x0 * w.y; acc[0][2] += x0 * w.z; acc[0][3] += x0 * w.w;
    acc[1][0] += x1 * w.x; acc[1][1] += x1 * w.y; acc[1][2] += x1 * w.z; acc[1][3] += x1 * w.w;
    acc[2][0] += x2 * w.x; acc[2][1] += x2 * w.y; acc[2][2] += x2 * w.z; acc[2][3] += x2 * w.w;
    acc[3][0] += x3 * w.x; acc[3][1] += x3 * w.y; acc[3][2] += x3 * w.z; acc[3][3] += x3 * w.w;
  }
  float4 b4 = *(const float4*)&bias[c0];
  for (int r = 0; r < 4; r++) {
    int row = row0 + r0 + r;
    if (row < M) {
      float4 o;
      o.x = acc[r][0] + b4.x; o.y = acc[r][1] + b4.y;
      o.z = acc[r][2] + b4.z; o.w = acc[r][3] + b4.w;
      *(float4*)&out[(size_t)row * 128 + c0] = o;
    }
  }
}

// ---------------- h3 = latent @ Wl3 (128x32) + b ----------------
__global__ __launch_bounds__(256) void gemm32_kernel(const float* __restrict__ X,
    const float* __restrict__ W, const float* __restrict__ bias,
    float* __restrict__ out, int M) {
  int t = blockIdx.x * 256 + threadIdx.x;
  int node = t >> 5, c = t & 31;
  if (node >= M) return;
  const float4* xp = (const float4*)&X[(size_t)node * 128];
  float acc = 0.f;
#pragma unroll
  for (int q = 0; q < 32; q++) {
    float4 x4 = xp[q];
    acc += x4.x * W[(q * 4 + 0) * 32 + c] + x4.y * W[(q * 4 + 1) * 32 + c]
         + x4.z * W[(q * 4 + 2) * 32 + c] + x4.w * W[(q * 4 + 3) * 32 + c];
  }
  out[(size_t)node * 32 + c] = acc + bias[c];
}

// ---------------- h2 = latent @ Wl2 (128x1) + b ----------------
__global__ __launch_bounds__(256) void gemv_kernel(const float* __restrict__ X,
    const float* __restrict__ w, const float* __restrict__ b0,
    float* __restrict__ out, int M) {
  int wv = (blockIdx.x * 256 + threadIdx.x) >> 6;
  int lane = threadIdx.x & 63;
  if (wv >= M) return;
  float2 xv = *(const float2*)&X[(size_t)wv * 128 + lane * 2];
  float2 wvv = *(const float2*)&w[lane * 2];
  float v = xv.x * wvv.x + xv.y * wvv.y;
#pragma unroll
  for (int off = 32; off; off >>= 1) v += __shfl_xor(v, off);
  if (lane == 0) out[wv] = v + b0[0];
}

// ---------------- layer-1 fused (wave/node, reg-We, 4-edge batches) ----------------
__global__ __launch_bounds__(256, 3) void fused1_kernel(const float* __restrict__ h,
    const int* __restrict__ src_csr, const int* __restrict__ eid,
    const int* __restrict__ row_start, const float* __restrict__ ea,
    const float* __restrict__ We, const float* __restrict__ att,
    const float* __restrict__ bias, float* __restrict__ out, int N) {
  int tid = threadIdx.x;
  int wv = (blockIdx.x * 256 + tid) >> 6;
  int lane = tid & 63;
  if (wv >= N) return;
  int l2 = lane * 2;
  float2 we[16];
#pragma unroll
  for (int k = 0; k < 16; k++) we[k] = *(const float2*)&We[k * 128 + l2];
  float2 attv = *(const float2*)&att[l2];
  float2 b2 = *(const float2*)&bias[l2];
  int start = row_start[wv];
  int deg = row_start[wv + 1] - start;
  if (deg == 0) {
    *(float2*)&out[(size_t)wv * 128 + l2] = b2;
    return;
  }
  float2 hi = *(const float2*)&h[(size_t)wv * 128 + l2];
  int e_l = 0, s_l = 0;
  if (lane < deg) { e_l = eid[start + lane]; s_l = src_csr[start + lane]; }
  int dcap = deg < 64 ? deg : 64;
  float m = -INFINITY, l = 0.f;
  float2 acc = make_float2(0.f, 0.f);
  for (int j0 = 0; j0 < deg; j0 += 4) {
    float2 hj[4];
    float4 A[4][4];
#pragma unroll
    for (int t = 0; t < 4; t++) {
      int j = j0 + t;
      int jc = (j < deg) ? j : j0;
      int e, s;
      if (jc < dcap) { e = __shfl(e_l, jc); s = __shfl(s_l, jc); }
      else { e = eid[start + jc]; s = src_csr[start + jc]; }
      hj[t] = *(const float2*)&h[(size_t)s * 128 + l2];
      const float4* eap = (const float4*)&ea[(size_t)e * 16];
      A[t][0] = eap[0]; A[t][1] = eap[1]; A[t][2] = eap[2]; A[t][3] = eap[3];
    }
    float sc[4];
#pragma unroll
    for (int t = 0; t < 4; t++) {
      float v0 = hi.x + hj[t].x, v1 = hi.y + hj[t].y;
#pragma unroll
      for (int q = 0; q < 4; q++) {
        float4 cq = A[t][q];
        v0 += cq.x * we[4 * q + 0].x; v1 += cq.x * we[4 * q + 0].y;
        v0 += cq.y * we[4 * q + 1].x; v1 += cq.y * we[4 * q + 1].y;
        v0 += cq.z * we[4 * q + 2].x; v1 += cq.z * we[4 * q + 2].y;
        v0 += cq.w * we[4 * q + 3].x; v1 += cq.w * we[4 * q + 3].y;
      }
      v0 = v0 >= 0.f ? v0 : NEG * v0;
      v1 = v1 >= 0.f ? v1 : NEG * v1;
      sc[t] = v0 * attv.x + v1 * attv.y;
    }
#pragma unroll
    for (int off = 32; off; off >>= 1) {
      sc[0] += __shfl_xor(sc[0], off);
      sc[1] += __shfl_xor(sc[1], off);
      sc[2] += __shfl_xor(sc[2], off);
      sc[3] += __shfl_xor(sc[3], off);
    }
    if (j0 + 1 >= deg) sc[1] = -INFINITY;
    if (j0 + 2 >= deg) sc[2] = -INFINITY;
    if (j0 + 3 >= deg) sc[3] = -INFINITY;
    float mb = fmaxf(fmaxf(sc[0], sc[1]), fmaxf(sc[2], sc[3]));
    float mn = fmaxf(m, mb);
    float scale = __expf(m - mn);      // first batch: exp(-inf)=0
    float w0 = __expf(sc[0] - mn);
    float w1 = __expf(sc[1] - mn);
    float w2 = __expf(sc[2] - mn);
    float w3 = __expf(sc[3] - mn);
    l = l * scale + ((w0 + w1) + (w2 + w3));
    acc.x = acc.x * scale + w0 * hj[0].x + w1 * hj[1].x + w2 * hj[2].x + w3 * hj[3].x;
    acc.y = acc.y * scale + w0 * hj[0].y + w1 * hj[1].y + w2 * hj[2].y + w3 * hj[3].y;
    m = mn;
  }
  float inv = 1.0f / (l + 1e-16f);
  float2 o;
  o.x = acc.x * inv + b2.x;
  o.y = acc.y * inv + b2.y;
  *(float2*)&out[(size_t)wv * 128 + l2] = o;
}

// ---------------- layers 2+3 fused (half-wave/edge, 2-edge batches per half) ----------------
__global__ __launch_bounds__(256, 4) void fused23_kernel(
    const float* __restrict__ h3, const float* __restrict__ h2,
    const int* __restrict__ src_csr, const int* __restrict__ eid,
    const int* __restrict__ row_start, const float* __restrict__ ea,
    const float* __restrict__ We3, const float* __restrict__ att3,
    const float* __restrict__ bias3, const float* __restrict__ We2,
    const float* __restrict__ att2, const float* __restrict__ bias2,
    float* __restrict__ out3, float* __restrict__ logits, int N) {
  int tid = threadIdx.x;
  int wv = (blockIdx.x * 256 + tid) >> 6;
  int lane = tid & 63;
  if (wv >= N) return;
  int c = lane & 31;
  int par = lane >> 5;
  float we3[16];
#pragma unroll
  for (int k = 0; k < 16; k++) we3[k] = We3[k * 32 + c];
  float we2[16];
#pragma unroll
  for (int k = 0; k < 16; k++) we2[k] = We2[k];
  float at3 = att3[c];
  float a2s = att2[0];
  float bi3 = bias3[c];
  int start = row_start[wv];
  int deg = row_start[wv + 1] - start;
  if (deg == 0) {
    if (par == 0) out3[(size_t)wv * 32 + c] = bi3;
    if (lane == 0) logits[wv] = bias2[0];
    return;
  }
  float hi3 = h3[(size_t)wv * 32 + c];
  float hi2 = h2[wv];
  int e_l = 0, s_l = 0;
  if (lane < deg) { e_l = eid[start + lane]; s_l = src_csr[start + lane]; }
  int dcap = deg < 64 ? deg : 64;
  float m3 = -INFINITY, l3 = 0.f, acc3 = 0.f;
  float m2 = -INFINITY, l2 = 0.f, acc2 = 0.f;
  // half-wave `par` handles edges j0+par and j0+par+2 each batch
  for (int j0 = 0; j0 < deg; j0 += 4) {
    int jA = j0 + par, jB = j0 + par + 2;
    float hj3[2], h2s[2];
    float4 B[2][4];
#pragma unroll
    for (int u = 0; u < 2; u++) {
      int j = u ? jB : jA;
      int jc = (j < deg) ? j : 0;
      int e, s;
      if (jc < dcap) { e = __shfl(e_l, jc); s = __shfl(s_l, jc); }
      else { e = eid[start + jc]; s = src_csr[start + jc]; }
      hj3[u] = h3[(size_t)s * 32 + c];
      h2s[u] = h2[s];
      const float4* eap = (const float4*)&ea[(size_t)e * 16];
      B[u][0] = eap[0]; B[u][1] = eap[1]; B[u][2] = eap[2]; B[u][3] = eap[3];
    }
    float t3[2], t2[2];
#pragma unroll
    for (int u = 0; u < 2; u++) {
      float4 c0 = B[u][0], c1 = B[u][1], c2 = B[u][2], c3 = B[u][3];
      float v3 = hi3 + hj3[u];
      v3 += c0.x * we3[0]  + c0.y * we3[1]  + c0.z * we3[2]  + c0.w * we3[3];
      v3 += c1.x * we3[4]  + c1.y * we3[5]  + c1.z * we3[6]  + c1.w * we3[7];
      v3 += c2.x * we3[8]  + c2.y * we3[9]  + c2.z * we3[10] + c2.w * we3[11];
      v3 += c3.x * we3[12] + c3.y * we3[13] + c3.z * we3[14] + c3.w * we3[15];
      v3 = v3 >= 0.f ? v3 : NEG * v3;
      t3[u] = v3 * at3;
      float v2 = hi2 + h2s[u];
      v2 += c0.x * we2[0]  + c0.y * we2[1]  + c0.z * we2[2]  + c0.w * we2[3];
      v2 += c1.x * we2[4]  + c1.y * we2[5]  + c1.z * we2[6]  + c1.w * we2[7];
      v2 += c2.x * we2[8]  + c2.y * we2[9]  + c2.z * we2[10] + c2.w * we2[11];
      v2 += c3.x * we2[12] + c3.y * we2[13] + c3.z * we2[14] + c3.w * we2[15];
      v2 = v2 >= 0.f ? v2 : NEG * v2;
      t2[u] = v2 * a2s;
    }
#pragma unroll
    for (int off = 16; off; off >>= 1) {
      t3[0] += __shfl_xor(t3[0], off);
      t3[1] += __shfl_xor(t3[1], off);
    }
    if (jA >= deg) { t3[0] = -INFINITY; t2[0] = -INFINITY; }
    if (jB >= deg) { t3[1] = -INFINITY; t2[1] = -INFINITY; }
    float mn3 = fmaxf(m3, fmaxf(t3[0], t3[1]));
    if (mn3 > -INFINITY) {
      float sc = __expf(m3 - mn3);
      float wa = __expf(t3[0] - mn3);
      float wb = __expf(t3[1] - mn3);
      l3 = l3 * sc + wa + wb;
      acc3 = acc3 * sc + wa * hj3[0] + wb * hj3[1];
      m3 = mn3;
    }
    float mn2 = fmaxf(m2, fmaxf(t2[0], t2[1]));
    if (mn2 > -INFINITY) {
      float sc = __expf(m2 - mn2);
      float wa = __expf(t2[0] - mn2);
      float wb = __expf(t2[1] - mn2);
      l2 = l2 * sc + wa + wb;
      acc2 = acc2 * sc + wa * h2s[0] + wb * h2s[1];
      m2 = mn2;
    }
  }
  // merge two half-wave states
  float m3o = __shfl_xor(m3, 32), l3o = __shfl_xor(l3, 32), acc3o = __shfl_xor(acc3, 32);
  float M3 = fmaxf(m3, m3o);
  float sA3 = (m3 == -INFINITY) ? 0.f : __expf(m3 - M3);
  float sB3 = (m3o == -INFINITY) ? 0.f : __expf(m3o - M3);
  float L3 = l3 * sA3 + l3o * sB3;
  float A3 = acc3 * sA3 + acc3o * sB3;
  float m2o = __shfl_xor(m2, 32), l2o = __shfl_xor(l2, 32), acc2o = __shfl_xor(acc2, 32);
  float M2 = fmaxf(m2, m2o);
  float sA2 = (m2 == -INFINITY) ? 0.f : __expf(m2 - M2);
  float sB2 = (m2o == -INFINITY) ? 0.f : __expf(m2o - M2);
  float L2 = l2 * sA2 + l2o * sB2;
  float A2 = acc2 * sA2 + acc2o * sB2;
  if (par == 0) out3[(size_t)wv * 32 + c] = A3 / (L3 + 1e-16f) + bi3;
  if (lane == 0) logits[wv] = A2 / (L2 + 1e-16f) + bias2[0];
}

// ---------------- node categorical: 64-block partial + 1-wave final ----------------
#define NSB 64
__global__ __launch_bounds__(256) void node_partial_kernel(const float* __restrict__ logits,
    int N, uint32_t ka, uint32_t kb,
    float* __restrict__ pB, int* __restrict__ pI,
    float* __restrict__ pM, float* __restrict__ pL) {
  int chunk = (N + NSB - 1) / NSB;
  int s0 = blockIdx.x * chunk;
  int s1 = s0 + chunk; if (s1 > N) s1 = N;
  int tid = threadIdx.x;
  float best = -INFINITY; int bi = 0x7fffffff;
  float m = -INFINITY, l = 0.f;
  for (int i = s0 + tid; i < s1; i += 256) {
    float lg = logits[i];
    float mn = fmaxf(m, lg);
    l = l * __expf(m - mn) + __expf(lg - mn);
    m = mn;
    float v = lg + gumbel_part(ka, kb, (uint32_t)i);
    if (v > best) { best = v; bi = i; }
  }
  __shared__ float sb[256], sm[256], sl[256];
  __shared__ int si[256];
  sb[tid] = best; si[tid] = bi; sm[tid] = m; sl[tid] = l;
  __syncthreads();
  for (int s = 128; s; s >>= 1) {
    if (tid < s) {
      if (sb[tid + s] > sb[tid] || (sb[tid + s] == sb[tid] && si[tid + s] < si[tid])) {
        sb[tid] = sb[tid + s]; si[tid] = si[tid + s];
      }
      float M = fmaxf(sm[tid], sm[tid + s]);
      float t0 = (sm[tid] == -INFINITY) ? 0.f : sl[tid] * __expf(sm[tid] - M);
      float t1 = (sm[tid + s] == -INFINITY) ? 0.f : sl[tid + s] * __expf(sm[tid + s] - M);
      sm[tid] = M; sl[tid] = t0 + t1;
    }
    __syncthreads();
  }
  if (tid == 0) { pB[blockIdx.x] = sb[0]; pI[blockIdx.x] = si[0]; pM[blockIdx.x] = sm[0]; pL[blockIdx.x] = sl[0]; }
}

__global__ __launch_bounds__(64) void node_final_kernel(const float* __restrict__ logits,
    const float* __restrict__ pB, const int* __restrict__ pI,
    const float* __restrict__ pM, const float* __restrict__ pL,
    float* __restrict__ scal) {
  int lane = threadIdx.x;
  float best = pB[lane]; int bi = pI[lane];
  float m = pM[lane]; float l = pL[lane];
#pragma unroll
  for (int off = 32; off; off >>= 1) {
    float ob = __shfl_xor(best, off); int oi = __shfl_xor(bi, off);
    if (ob > best || (ob == best && oi < bi)) { best = ob; bi = oi; }
    float om = __shfl_xor(m, off); float ol = __shfl_xor(l, off);
    float M = fmaxf(m, om);
    float t0 = (m == -INFINITY) ? 0.f : l * __expf(m - M);
    float t1 = (om == -INFINITY) ? 0.f : ol * __expf(om - M);
    m = M; l = t0 + t1;
  }
  if (lane == 0) {
    ((int*)scal)[0] = bi;
    scal[3] = logits[bi] - (m + logf(l));
  }
}

// ---------------- action categorical + output ----------------
__global__ __launch_bounds__(64) void action_kernel(const float* __restrict__ out3,
    const float* __restrict__ scal, uint32_t ka, uint32_t kb,
    float* __restrict__ dout, int out_size) {
  int lane = threadIdx.x;
  int sel = ((const int*)scal)[0];
  float v = -INFINITY, noisy = -INFINITY;
  if (lane < 32) {
    v = out3[(size_t)sel * 32 + lane];
    noisy = v + gumbel_part(ka, kb, (uint32_t)lane);
  }
  int idx = lane;
  float nv = noisy;
#pragma unroll
  for (int off = 32; off; off >>= 1) {
    float ov = __shfl_xor(nv, off);
    int oi = __shfl_xor(idx, off);
    if (ov > nv || (ov == nv && oi < idx)) { nv = ov; idx = oi; }
  }
  float vm = v;
#pragma unroll
  for (int off = 32; off; off >>= 1) vm = fmaxf(vm, __shfl_xor(vm, off));
  float ex = (lane < 32) ? expf(v - vm) : 0.f;
#pragma unroll
  for (int off = 32; off; off >>= 1) ex += __shfl_xor(ex, off);
  float vsel = __shfl(v, idx);
  if (lane == 0) {
    float action_lp = vsel - vm - logf(ex);
    dout[0] = (float)sel;
    dout[1] = (float)idx;
    dout[2] = scal[3] + action_lp;
  }
  for (int i = 3 + lane; i < out_size; i += 64) dout[i] = 0.f;
}

extern "C" void kernel_launch(void* const* d_in, const int* in_sizes, int n_in,
                              void* d_out, int out_size, void* d_ws, size_t ws_size,
                              hipStream_t stream) {
  const float* x     = (const float*)d_in[0];
  const int*   ei    = (const int*)d_in[1];
  const float* ea    = (const float*)d_in[2];
  const float* Wl1   = (const float*)d_in[3];
  const float* bl1   = (const float*)d_in[4];
  const float* We1   = (const float*)d_in[5];
  const float* att1  = (const float*)d_in[6];
  const float* bias1 = (const float*)d_in[7];
  const float* Wl2   = (const float*)d_in[8];
  const float* bl2   = (const float*)d_in[9];
  const float* We2   = (const float*)d_in[10];
  const float* att2  = (const float*)d_in[11];
  const float* bias2 = (const float*)d_in[12];
  const float* Wl3   = (const float*)d_in[13];
  const float* bl3   = (const float*)d_in[14];
  const float* We3   = (const float*)d_in[15];
  const float* att3  = (const float*)d_in[16];
  const float* bias3 = (const float*)d_in[17];
  int N = in_sizes[0] / 128;
  int E = in_sizes[1] / 2;
  float* out = (float*)d_out;

  char* p = (char*)d_ws;
  auto alloc = [&](size_t bytes) -> char* {
    char* r = p; p += (bytes + 255) & ~(size_t)255; return r;
  };
  float* h1      = (float*)alloc((size_t)N * 128 * 4);
  float* latent  = (float*)alloc((size_t)N * 128 * 4);
  float* h3      = (float*)alloc((size_t)N * 32 * 4);
  float* h2      = (float*)alloc((size_t)N * 4);
  float* logits  = (float*)alloc((size_t)N * 4);
  float* out3    = (float*)alloc((size_t)N * 32 * 4);
  int* counts    = (int*)alloc((size_t)N * 4);
  int* row_start = (int*)alloc((size_t)(N + 1) * 4);
  int* cursor    = (int*)alloc((size_t)N * 4);
  int* eid       = (int*)alloc((size_t)E * 4);
  int* src_csr   = (int*)alloc((size_t)E * 4);
  float* pB      = (float*)alloc(NSB * 4);
  int*   pI      = (int*)alloc(NSB * 4);
  float* pM      = (float*)alloc(NSB * 4);
  float* pL      = (float*)alloc(NSB * 4);
  float* scal    = (float*)alloc(64);
  (void)ws_size; (void)n_in;

  // JAX PRNG (partitionable): key(42)=(0,42); subkey_i = TF(key,(0,i))
  uint32_t k1a, k1b, k2a, k2b;
  threefry2x32(0u, 42u, 0u, 0u, &k1a, &k1b);
  threefry2x32(0u, 42u, 0u, 1u, &k2a, &k2b);

  hipMemsetAsync(counts, 0, (size_t)N * 4, stream);
  count_kernel<<<(E + 255) / 256, 256, 0, stream>>>(ei, E, counts);
  scan_kernel<<<1, 1024, 0, stream>>>(counts, row_start, cursor, N, E);
  scatter_kernel<<<(E + 255) / 256, 256, 0, stream>>>(ei, E, cursor, eid, src_csr);

  gemm128_kernel<<<(N + 31) / 32, 256, 0, stream>>>(x, Wl1, bl1, h1, N);
  fused1_kernel<<<(N + 3) / 4, 256, 0, stream>>>(h1, src_csr, eid, row_start,
                                                 ea, We1, att1, bias1, latent, N);

  gemm32_kernel<<<((size_t)N * 32 + 255) / 256, 256, 0, stream>>>(latent, Wl3, bl3, h3, N);
  gemv_kernel<<<(N + 3) / 4, 256, 0, stream>>>(latent, Wl2, bl2, h2, N);

  fused23_kernel<<<(N + 3) / 4, 256, 0, stream>>>(h3, h2, src_csr, eid, row_start,
                                                  ea, We3, att3, bias3, We2, att2, bias2,
                                                  out3, logits, N);

  node_partial_kernel<<<NSB, 256, 0, stream>>>(logits, N, k1a, k1b, pB, pI, pM, pL);
  node_final_kernel<<<1, 64, 0, stream>>>(logits, pB, pI, pM, pL, scal);
  action_kernel<<<1, 64, 0, stream>>>(out3, scal, k2a, k2b, out, out_size);
}

// Round 7
// 665.776 us; speedup vs baseline: 1.0843x; 1.0843x over previous
//
#include <hip/hip_runtime.h>
#include <stdint.h>
#include <math.h>

#define NEG 0.2f
#define TINYF 1.1754943508222875e-38f

// ---------------- Threefry-2x32-20 (matches JAX) ----------------
__host__ __device__ inline void threefry2x32(uint32_t k0, uint32_t k1,
                                             uint32_t x0, uint32_t x1,
                                             uint32_t* o0, uint32_t* o1) {
  uint32_t ks0 = k0, ks1 = k1, ks2 = k0 ^ k1 ^ 0x1BD11BDAu;
  x0 += ks0; x1 += ks1;
#define RR(r) { x0 += x1; x1 = (x1 << (r)) | (x1 >> (32 - (r))); x1 ^= x0; }
  RR(13) RR(15) RR(26) RR(6)
  x0 += ks1; x1 += ks2 + 1u;
  RR(17) RR(29) RR(16) RR(24)
  x0 += ks2; x1 += ks0 + 2u;
  RR(13) RR(15) RR(26) RR(6)
  x0 += ks0; x1 += ks1 + 3u;
  RR(17) RR(29) RR(16) RR(24)
  x0 += ks1; x1 += ks2 + 4u;
  RR(13) RR(15) RR(26) RR(6)
  x0 += ks2; x1 += ks0 + 5u;
#undef RR
  *o0 = x0; *o1 = x1;
}

// jax_threefry_partitionable=True random_bits, bit_width=32:
//   bits[i] = o0 ^ o1 of TF(key, (0, i))   [verified exact: R3-R6 pass]
__device__ inline float gumbel_part(uint32_t ka, uint32_t kb, uint32_t i) {
  uint32_t o0, o1;
  threefry2x32(ka, kb, 0u, i, &o0, &o1);
  uint32_t bits = o0 ^ o1;
  float f = __uint_as_float((bits >> 9) | 0x3f800000u) - 1.0f;
  float u = fmaxf(TINYF, f + TINYF);
  return -logf(-logf(u));
}

// ---------------- CSR build ----------------
__global__ void count_kernel(const int* __restrict__ ei, int E, int* __restrict__ counts) {
  int e = blockIdx.x * blockDim.x + threadIdx.x;
  if (e < E) atomicAdd(&counts[ei[E + e]], 1);
}

// wave-shuffle scan
__global__ __launch_bounds__(1024) void scan_kernel(const int* __restrict__ counts,
    int* __restrict__ row_start, int* __restrict__ cursor, int N, int E) {
  __shared__ int wsum[16];
  __shared__ int base_s;
  int tid = threadIdx.x;
  int lane = tid & 63, wv = tid >> 6;
  if (tid == 0) base_s = 0;
  __syncthreads();
  for (int chunk = 0; chunk < N; chunk += 1024) {
    int i = chunk + tid;
    int v = (i < N) ? counts[i] : 0;
    int incl = v;
#pragma unroll
    for (int off = 1; off < 64; off <<= 1) {
      int t = __shfl_up(incl, off);
      if (lane >= off) incl += t;
    }
    if (lane == 63) wsum[wv] = incl;
    __syncthreads();
    if (wv == 0) {
      int x = (lane < 16) ? wsum[lane] : 0;
#pragma unroll
      for (int off = 1; off < 16; off <<= 1) {
        int t = __shfl_up(x, off);
        if (lane >= off) x += t;
      }
      if (lane < 16) wsum[lane] = x;
    }
    __syncthreads();
    int waveoff = (wv == 0) ? 0 : wsum[wv - 1];
    int base = base_s;
    int excl = base + waveoff + incl - v;
    if (i < N) { row_start[i] = excl; cursor[i] = excl; }
    __syncthreads();
    if (tid == 1023) base_s = base + wsum[15];
    __syncthreads();
  }
  if (tid == 0) row_start[N] = base_s;
}

// scatter: build src_csr AND permute edge attributes into CSR order
// (converts fused kernels' random 64B ea reads into sequential reads;
//  scattered writes here are not on a latency chain)
__global__ void scatter_kernel(const int* __restrict__ ei, const float* __restrict__ ea,
                               int E, int* __restrict__ cursor,
                               int* __restrict__ src_csr, float* __restrict__ ea_csr) {
  int e = blockIdx.x * blockDim.x + threadIdx.x;
  if (e < E) {
    int d = ei[E + e];
    int p = atomicAdd(&cursor[d], 1);
    src_csr[p] = ei[e];
    const float4* s4 = (const float4*)&ea[(size_t)e * 16];
    float4* d4 = (float4*)&ea_csr[(size_t)p * 16];
    float4 t0 = s4[0], t1 = s4[1], t2 = s4[2], t3 = s4[3];
    d4[0] = t0; d4[1] = t1; d4[2] = t2; d4[3] = t3;
  }
}

// ---------------- h = X @ W (128x128) + b ----------------
__global__ __launch_bounds__(256) void gemm128_kernel(const float* __restrict__ X,
    const float* __restrict__ W, const float* __restrict__ bias,
    float* __restrict__ out, int M) {
  __shared__ float xs[128][33];
  int row0 = blockIdx.x * 32;
  int tid = threadIdx.x;
  for (int idx = tid; idx < 32 * 128; idx += 256) {
    int r = idx >> 7;
    int k = idx & 127;
    int row = row0 + r;
    xs[k][r] = (row < M) ? X[(size_t)row * 128 + k] : 0.0f;
  }
  __syncthreads();
  int tc = tid & 31, tr = tid >> 5;
  int c0 = tc * 4, r0 = tr * 4;
  float acc[4][4] = {};
#pragma unroll 4
  for (int k = 0; k < 128; k++) {
    float4 w = *(const float4*)&W[k * 128 + c0];
    float x0 = xs[k][r0], x1 = xs[k][r0 + 1], x2 = xs[k][r0 + 2], x3 = xs[k][r0 + 3];
    acc[0][0] += x0 * w.x; acc[0][1] += x0 * w.y; acc[0][2] += x0 * w.z; acc[0][3] += x0 * w.w;
    acc[1][0] += x1 * w.x; acc[1][1] += x1 * w.y; acc[1][2] += x1 * w.z; acc[1][3] += x1 * w.w;
    acc[2][0] += x2 * w.x; acc[2][1] += x2 * w.y; acc[2][2] += x2 * w.z; acc[2][3] += x2 * w.w;
    acc[3][0] += x3 * w.x; acc[3][1] += x3 * w.y; acc[3][2] += x3 * w.z; acc[3][3] += x3 * w.w;
  }
  float4 b4 = *(const float4*)&bias[c0];
  for (int r = 0; r < 4; r++) {
    int row = row0 + r0 + r;
    if (row < M) {
      float4 o;
      o.x = acc[r][0] + b4.x; o.y = acc[r][1] + b4.y;
      o.z = acc[r][2] + b4.z; o.w = acc[r][3] + b4.w;
      *(float4*)&out[(size_t)row * 128 + c0] = o;
    }
  }
}

// ---------------- h3 = latent @ Wl3 (128x32) + b ----------------
__global__ __launch_bounds__(256) void gemm32_kernel(const float* __restrict__ X,
    const float* __restrict__ W, const float* __restrict__ bias,
    float* __restrict__ out, int M) {
  int t = blockIdx.x * 256 + threadIdx.x;
  int node = t >> 5, c = t & 31;
  if (node >= M) return;
  const float4* xp = (const float4*)&X[(size_t)node * 128];
  float acc = 0.f;
#pragma unroll
  for (int q = 0; q < 32; q++) {
    float4 x4 = xp[q];
    acc += x4.x * W[(q * 4 + 0) * 32 + c] + x4.y * W[(q * 4 + 1) * 32 + c]
         + x4.z * W[(q * 4 + 2) * 32 + c] + x4.w * W[(q * 4 + 3) * 32 + c];
  }
  out[(size_t)node * 32 + c] = acc + bias[c];
}

// ---------------- h2 = latent @ Wl2 (128x1) + b ----------------
__global__ __launch_bounds__(256) void gemv_kernel(const float* __restrict__ X,
    const float* __restrict__ w, const float* __restrict__ b0,
    float* __restrict__ out, int M) {
  int wv = (blockIdx.x * 256 + threadIdx.x) >> 6;
  int lane = threadIdx.x & 63;
  if (wv >= M) return;
  float2 xv = *(const float2*)&X[(size_t)wv * 128 + lane * 2];
  float2 wvv = *(const float2*)&w[lane * 2];
  float v = xv.x * wvv.x + xv.y * wvv.y;
#pragma unroll
  for (int off = 32; off; off >>= 1) v += __shfl_xor(v, off);
  if (lane == 0) out[wv] = v + b0[0];
}

// ---------------- layer-1 fused (HALF-wave per node, float4 lanes, LDS We) ----------------
__global__ __launch_bounds__(256) void fused1_kernel(const float* __restrict__ h,
    const int* __restrict__ src_csr, const int* __restrict__ row_start,
    const float* __restrict__ ea_csr,
    const float* __restrict__ We, const float* __restrict__ att,
    const float* __restrict__ bias, float* __restrict__ out, int N) {
  __shared__ float WeS[2048];
  int tid = threadIdx.x;
  for (int i = tid; i < 2048; i += 256) WeS[i] = We[i];
  __syncthreads();
  int hw = (blockIdx.x * 256 + tid) >> 5;   // half-wave = one node
  int lane = tid & 31;
  if (hw >= N) return;
  int c4 = lane * 4;
  float4 attv = *(const float4*)&att[c4];
  float4 b4 = *(const float4*)&bias[c4];
  int start = row_start[hw];
  int deg = row_start[hw + 1] - start;
  if (deg == 0) {
    *(float4*)&out[(size_t)hw * 128 + c4] = b4;
    return;
  }
  float4 hi = *(const float4*)&h[(size_t)hw * 128 + c4];
  int s_l = (lane < deg) ? src_csr[start + lane] : 0;
  int dcap = deg < 32 ? deg : 32;
  const float4* eap = (const float4*)&ea_csr[(size_t)start * 16];
  float m = -INFINITY, l = 0.f;
  float4 acc = make_float4(0.f, 0.f, 0.f, 0.f);
  for (int j = 0; j < deg; j++) {
    int s = (j < dcap) ? __shfl(s_l, j, 32) : src_csr[start + j];
    float4 hj = *(const float4*)&h[(size_t)s * 128 + c4];
    float4 v;
    v.x = hi.x + hj.x; v.y = hi.y + hj.y; v.z = hi.z + hj.z; v.w = hi.w + hj.w;
#pragma unroll
    for (int q = 0; q < 4; q++) {
      float4 aq = eap[(size_t)j * 4 + q];
      float4 w0 = *(const float4*)&WeS[(4 * q + 0) * 128 + c4];
      float4 w1 = *(const float4*)&WeS[(4 * q + 1) * 128 + c4];
      float4 w2 = *(const float4*)&WeS[(4 * q + 2) * 128 + c4];
      float4 w3 = *(const float4*)&WeS[(4 * q + 3) * 128 + c4];
      v.x += aq.x * w0.x + aq.y * w1.x + aq.z * w2.x + aq.w * w3.x;
      v.y += aq.x * w0.y + aq.y * w1.y + aq.z * w2.y + aq.w * w3.y;
      v.z += aq.x * w0.z + aq.y * w1.z + aq.z * w2.z + aq.w * w3.z;
      v.w += aq.x * w0.w + aq.y * w1.w + aq.z * w2.w + aq.w * w3.w;
    }
    v.x = v.x >= 0.f ? v.x : NEG * v.x;
    v.y = v.y >= 0.f ? v.y : NEG * v.y;
    v.z = v.z >= 0.f ? v.z : NEG * v.z;
    v.w = v.w >= 0.f ? v.w : NEG * v.w;
    float sc = v.x * attv.x + v.y * attv.y + v.z * attv.z + v.w * attv.w;
#pragma unroll
    for (int off = 16; off; off >>= 1) sc += __shfl_xor(sc, off);
    float mn = fmaxf(m, sc);
    float scale = __expf(m - mn);   // first edge: exp(-inf)=0
    float w = __expf(sc - mn);
    l = l * scale + w;
    acc.x = acc.x * scale + w * hj.x;
    acc.y = acc.y * scale + w * hj.y;
    acc.z = acc.z * scale + w * hj.z;
    acc.w = acc.w * scale + w * hj.w;
    m = mn;
  }
  float inv = 1.0f / (l + 1e-16f);
  float4 o;
  o.x = acc.x * inv + b4.x;
  o.y = acc.y * inv + b4.y;
  o.z = acc.z * inv + b4.z;
  o.w = acc.w * inv + b4.w;
  *(float4*)&out[(size_t)hw * 128 + c4] = o;
}

// ---------------- layers 2+3 fused (wave/node, half-wave/edge, LDS We, simple loop) ----------------
__global__ __launch_bounds__(256) void fused23_kernel(
    const float* __restrict__ h3, const float* __restrict__ h2,
    const int* __restrict__ src_csr, const int* __restrict__ row_start,
    const float* __restrict__ ea_csr,
    const float* __restrict__ We3, const float* __restrict__ att3,
    const float* __restrict__ bias3, const float* __restrict__ We2,
    const float* __restrict__ att2, const float* __restrict__ bias2,
    float* __restrict__ out3, float* __restrict__ logits, int N) {
  __shared__ float We3S[512];
  __shared__ float att3S[32];
  __shared__ float We2S[16];
  int tid = threadIdx.x;
  for (int i = tid; i < 512; i += 256) We3S[i] = We3[i];
  if (tid < 32) att3S[tid] = att3[tid];
  if (tid < 16) We2S[tid] = We2[tid];
  __syncthreads();
  int wv = (blockIdx.x * 256 + tid) >> 6;
  int lane = tid & 63;
  if (wv >= N) return;
  int c = lane & 31;
  int par = lane >> 5;
  float bi3 = bias3[c];
  int start = row_start[wv];
  int deg = row_start[wv + 1] - start;
  if (deg == 0) {
    if (par == 0) out3[(size_t)wv * 32 + c] = bi3;
    if (lane == 0) logits[wv] = bias2[0];
    return;
  }
  float at3 = att3S[c];
  float a2s = att2[0];
  float hi3 = h3[(size_t)wv * 32 + c];
  float hi2 = h2[wv];
  int s_l = (lane < deg) ? src_csr[start + lane] : 0;
  int dcap = deg < 64 ? deg : 64;
  const float4* eap = (const float4*)&ea_csr[(size_t)start * 16];
  float m3 = -INFINITY, l3 = 0.f, acc3 = 0.f;
  float m2 = -INFINITY, l2 = 0.f, acc2 = 0.f;
  // half-wave `par` handles edges par, par+2, par+4, ...
  for (int j = par; j < deg; j += 2) {
    int s = (j < dcap) ? __shfl(s_l, j) : src_csr[start + j];
    float hj3 = h3[(size_t)s * 32 + c];
    float h2s = h2[s];
    float4 c0 = eap[(size_t)j * 4 + 0];
    float4 c1 = eap[(size_t)j * 4 + 1];
    float4 c2 = eap[(size_t)j * 4 + 2];
    float4 c3 = eap[(size_t)j * 4 + 3];
    float v3 = hi3 + hj3;
    v3 += c0.x * We3S[0 * 32 + c]  + c0.y * We3S[1 * 32 + c]  + c0.z * We3S[2 * 32 + c]  + c0.w * We3S[3 * 32 + c];
    v3 += c1.x * We3S[4 * 32 + c]  + c1.y * We3S[5 * 32 + c]  + c1.z * We3S[6 * 32 + c]  + c1.w * We3S[7 * 32 + c];
    v3 += c2.x * We3S[8 * 32 + c]  + c2.y * We3S[9 * 32 + c]  + c2.z * We3S[10 * 32 + c] + c2.w * We3S[11 * 32 + c];
    v3 += c3.x * We3S[12 * 32 + c] + c3.y * We3S[13 * 32 + c] + c3.z * We3S[14 * 32 + c] + c3.w * We3S[15 * 32 + c];
    v3 = v3 >= 0.f ? v3 : NEG * v3;
    float t3 = v3 * at3;
#pragma unroll
    for (int off = 16; off; off >>= 1) t3 += __shfl_xor(t3, off);
    float v2 = hi2 + h2s;
    v2 += c0.x * We2S[0]  + c0.y * We2S[1]  + c0.z * We2S[2]  + c0.w * We2S[3];
    v2 += c1.x * We2S[4]  + c1.y * We2S[5]  + c1.z * We2S[6]  + c1.w * We2S[7];
    v2 += c2.x * We2S[8]  + c2.y * We2S[9]  + c2.z * We2S[10] + c2.w * We2S[11];
    v2 += c3.x * We2S[12] + c3.y * We2S[13] + c3.z * We2S[14] + c3.w * We2S[15];
    v2 = v2 >= 0.f ? v2 : NEG * v2;
    float t2 = v2 * a2s;
    float mn3 = fmaxf(m3, t3);
    float sc3 = __expf(m3 - mn3);
    float w3 = __expf(t3 - mn3);
    l3 = l3 * sc3 + w3;
    acc3 = acc3 * sc3 + w3 * hj3;
    m3 = mn3;
    float mn2 = fmaxf(m2, t2);
    float sc2 = __expf(m2 - mn2);
    float w2 = __expf(t2 - mn2);
    l2 = l2 * sc2 + w2;
    acc2 = acc2 * sc2 + w2 * h2s;
    m2 = mn2;
  }
  // merge two half-wave states
  float m3o = __shfl_xor(m3, 32), l3o = __shfl_xor(l3, 32), acc3o = __shfl_xor(acc3, 32);
  float M3 = fmaxf(m3, m3o);
  float sA3 = (m3 == -INFINITY) ? 0.f : __expf(m3 - M3);
  float sB3 = (m3o == -INFINITY) ? 0.f : __expf(m3o - M3);
  float L3 = l3 * sA3 + l3o * sB3;
  float A3 = acc3 * sA3 + acc3o * sB3;
  float m2o = __shfl_xor(m2, 32), l2o = __shfl_xor(l2, 32), acc2o = __shfl_xor(acc2, 32);
  float M2 = fmaxf(m2, m2o);
  float sA2 = (m2 == -INFINITY) ? 0.f : __expf(m2 - M2);
  float sB2 = (m2o == -INFINITY) ? 0.f : __expf(m2o - M2);
  float L2 = l2 * sA2 + l2o * sB2;
  float A2 = acc2 * sA2 + acc2o * sB2;
  if (par == 0) out3[(size_t)wv * 32 + c] = A3 / (L3 + 1e-16f) + bi3;
  if (lane == 0) logits[wv] = A2 / (L2 + 1e-16f) + bias2[0];
}

// ---------------- node categorical: 64-block partial + 1-wave final ----------------
#define NSB 64
__global__ __launch_bounds__(256) void node_partial_kernel(const float* __restrict__ logits,
    int N, uint32_t ka, uint32_t kb,
    float* __restrict__ pB, int* __restrict__ pI,
    float* __restrict__ pM, float* __restrict__ pL) {
  int chunk = (N + NSB - 1) / NSB;
  int s0 = blockIdx.x * chunk;
  int s1 = s0 + chunk; if (s1 > N) s1 = N;
  int tid = threadIdx.x;
  float best = -INFINITY; int bi = 0x7fffffff;
  float m = -INFINITY, l = 0.f;
  for (int i = s0 + tid; i < s1; i += 256) {
    float lg = logits[i];
    float mn = fmaxf(m, lg);
    l = l * __expf(m - mn) + __expf(lg - mn);
    m = mn;
    float v = lg + gumbel_part(ka, kb, (uint32_t)i);
    if (v > best) { best = v; bi = i; }
  }
  __shared__ float sb[256], sm[256], sl[256];
  __shared__ int si[256];
  sb[tid] = best; si[tid] = bi; sm[tid] = m; sl[tid] = l;
  __syncthreads();
  for (int s = 128; s; s >>= 1) {
    if (tid < s) {
      if (sb[tid + s] > sb[tid] || (sb[tid + s] == sb[tid] && si[tid + s] < si[tid])) {
        sb[tid] = sb[tid + s]; si[tid] = si[tid + s];
      }
      float M = fmaxf(sm[tid], sm[tid + s]);
      float t0 = (sm[tid] == -INFINITY) ? 0.f : sl[tid] * __expf(sm[tid] - M);
      float t1 = (sm[tid + s] == -INFINITY) ? 0.f : sl[tid + s] * __expf(sm[tid + s] - M);
      sm[tid] = M; sl[tid] = t0 + t1;
    }
    __syncthreads();
  }
  if (tid == 0) { pB[blockIdx.x] = sb[0]; pI[blockIdx.x] = si[0]; pM[blockIdx.x] = sm[0]; pL[blockIdx.x] = sl[0]; }
}

__global__ __launch_bounds__(64) void node_final_kernel(const float* __restrict__ logits,
    const float* __restrict__ pB, const int* __restrict__ pI,
    const float* __restrict__ pM, const float* __restrict__ pL,
    float* __restrict__ scal) {
  int lane = threadIdx.x;
  float best = pB[lane]; int bi = pI[lane];
  float m = pM[lane]; float l = pL[lane];
#pragma unroll
  for (int off = 32; off; off >>= 1) {
    float ob = __shfl_xor(best, off); int oi = __shfl_xor(bi, off);
    if (ob > best || (ob == best && oi < bi)) { best = ob; bi = oi; }
    float om = __shfl_xor(m, off); float ol = __shfl_xor(l, off);
    float M = fmaxf(m, om);
    float t0 = (m == -INFINITY) ? 0.f : l * __expf(m - M);
    float t1 = (om == -INFINITY) ? 0.f : ol * __expf(om - M);
    m = M; l = t0 + t1;
  }
  if (lane == 0) {
    ((int*)scal)[0] = bi;
    scal[3] = logits[bi] - (m + logf(l));
  }
}

// ---------------- action categorical + output ----------------
__global__ __launch_bounds__(64) void action_kernel(const float* __restrict__ out3,
    const float* __restrict__ scal, uint32_t ka, uint32_t kb,
    float* __restrict__ dout, int out_size) {
  int lane = threadIdx.x;
  int sel = ((const int*)scal)[0];
  float v = -INFINITY, noisy = -INFINITY;
  if (lane < 32) {
    v = out3[(size_t)sel * 32 + lane];
    noisy = v + gumbel_part(ka, kb, (uint32_t)lane);
  }
  int idx = lane;
  float nv = noisy;
#pragma unroll
  for (int off = 32; off; off >>= 1) {
    float ov = __shfl_xor(nv, off);
    int oi = __shfl_xor(idx, off);
    if (ov > nv || (ov == nv && oi < idx)) { nv = ov; idx = oi; }
  }
  float vm = v;
#pragma unroll
  for (int off = 32; off; off >>= 1) vm = fmaxf(vm, __shfl_xor(vm, off));
  float ex = (lane < 32) ? expf(v - vm) : 0.f;
#pragma unroll
  for (int off = 32; off; off >>= 1) ex += __shfl_xor(ex, off);
  float vsel = __shfl(v, idx);
  if (lane == 0) {
    float action_lp = vsel - vm - logf(ex);
    dout[0] = (float)sel;
    dout[1] = (float)idx;
    dout[2] = scal[3] + action_lp;
  }
  for (int i = 3 + lane; i < out_size; i += 64) dout[i] = 0.f;
}

extern "C" void kernel_launch(void* const* d_in, const int* in_sizes, int n_in,
                              void* d_out, int out_size, void* d_ws, size_t ws_size,
                              hipStream_t stream) {
  const float* x     = (const float*)d_in[0];
  const int*   ei    = (const int*)d_in[1];
  const float* ea    = (const float*)d_in[2];
  const float* Wl1   = (const float*)d_in[3];
  const float* bl1   = (const float*)d_in[4];
  const float* We1   = (const float*)d_in[5];
  const float* att1  = (const float*)d_in[6];
  const float* bias1 = (const float*)d_in[7];
  const float* Wl2   = (const float*)d_in[8];
  const float* bl2   = (const float*)d_in[9];
  const float* We2   = (const float*)d_in[10];
  const float* att2  = (const float*)d_in[11];
  const float* bias2 = (const float*)d_in[12];
  const float* Wl3   = (const float*)d_in[13];
  const float* bl3   = (const float*)d_in[14];
  const float* We3   = (const float*)d_in[15];
  const float* att3  = (const float*)d_in[16];
  const float* bias3 = (const float*)d_in[17];
  int N = in_sizes[0] / 128;
  int E = in_sizes[1] / 2;
  float* out = (float*)d_out;

  char* p = (char*)d_ws;
  auto alloc = [&](size_t bytes) -> char* {
    char* r = p; p += (bytes + 255) & ~(size_t)255; return r;
  };
  float* h1      = (float*)alloc((size_t)N * 128 * 4);
  float* latent  = (float*)alloc((size_t)N * 128 * 4);
  float* h3      = (float*)alloc((size_t)N * 32 * 4);
  float* h2      = (float*)alloc((size_t)N * 4);
  float* logits  = (float*)alloc((size_t)N * 4);
  float* out3    = (float*)alloc((size_t)N * 32 * 4);
  int* counts    = (int*)alloc((size_t)N * 4);
  int* row_start = (int*)alloc((size_t)(N + 1) * 4);
  int* cursor    = (int*)alloc((size_t)N * 4);
  int* src_csr   = (int*)alloc((size_t)E * 4);
  float* ea_csr  = (float*)alloc((size_t)E * 16 * 4);
  float* pB      = (float*)alloc(NSB * 4);
  int*   pI      = (int*)alloc(NSB * 4);
  float* pM      = (float*)alloc(NSB * 4);
  float* pL      = (float*)alloc(NSB * 4);
  float* scal    = (float*)alloc(64);
  (void)ws_size; (void)n_in;

  // JAX PRNG (partitionable): key(42)=(0,42); subkey_i = TF(key,(0,i))
  uint32_t k1a, k1b, k2a, k2b;
  threefry2x32(0u, 42u, 0u, 0u, &k1a, &k1b);
  threefry2x32(0u, 42u, 0u, 1u, &k2a, &k2b);

  hipMemsetAsync(counts, 0, (size_t)N * 4, stream);
  count_kernel<<<(E + 255) / 256, 256, 0, stream>>>(ei, E, counts);
  scan_kernel<<<1, 1024, 0, stream>>>(counts, row_start, cursor, N, E);
  scatter_kernel<<<(E + 255) / 256, 256, 0, stream>>>(ei, ea, E, cursor, src_csr, ea_csr);

  gemm128_kernel<<<(N + 31) / 32, 256, 0, stream>>>(x, Wl1, bl1, h1, N);
  fused1_kernel<<<(N + 7) / 8, 256, 0, stream>>>(h1, src_csr, row_start,
                                                 ea_csr, We1, att1, bias1, latent, N);

  gemm32_kernel<<<((size_t)N * 32 + 255) / 256, 256, 0, stream>>>(latent, Wl3, bl3, h3, N);
  gemv_kernel<<<(N + 3) / 4, 256, 0, stream>>>(latent, Wl2, bl2, h2, N);

  fused23_kernel<<<(N + 3) / 4, 256, 0, stream>>>(h3, h2, src_csr, row_start, ea_csr,
                                                  We3, att3, bias3, We2, att2, bias2,
                                                  out3, logits, N);

  node_partial_kernel<<<NSB, 256, 0, stream>>>(logits, N, k1a, k1b, pB, pI, pM, pL);
  node_final_kernel<<<1, 64, 0, stream>>>(logits, pB, pI, pM, pL, scal);
  action_kernel<<<1, 64, 0, stream>>>(out3, scal, k2a, k2b, out, out_size);
}